// Round 1
// baseline (100.109 us; speedup 1.0000x reference)
//
#include <hip/hip_runtime.h>

#define K    5
#define KK   25
#define H    160
#define W    160
#define C    64
#define BS   4
#define HW   (H * W)

#define TX   32          // tile width (pixels)
#define TY   8           // tile height (rows)
#define CPB  8           // channels per block
#define CPW  2           // channels per thread (= per wave)
#define BLK  256

#define FR   (TY + 4)    // fm rows staged (2 halo top + 2 bottom) = 12
#define FS   46          // fm LDS row stride: conflict-free b64 window reads (R7)

// R10 = R9 with the block barrier REMOVED. Observation: wave w only ever
// computes (and reads from LDS) channels {2w, 2w+1} -- the cooperative
// 8-channel staging + __syncthreads() was the only cross-wave coupling, and it
// phase-locks all 4 waves on the slowest staged load (R7-R9: all pipes <35%
// busy, latency-bound). Now each wave stages its OWN 2 channels into its own
// LDS region (disjoint by construction: region index uses c0), so no barrier
// is needed at all -- ds_write -> ds_read within a wave is ordered by
// lgkmcnt. Staging of one wave overlaps compute of others freely.
// Traffic, LDS size (17.7KB), coalescing and the FS=46 conflict-free window
// reads are unchanged from R9.
__global__ __launch_bounds__(BLK) void kconv_kernel(
    const float* __restrict__ fm,
    const float* __restrict__ kern,
    const int*  __restrict__ dil,
    float* __restrict__ out)
{
    __shared__ float fmlds[CPB * FR * FS];   // 17664 B

    const int tid   = threadIdx.x;
    const int gx    = blockIdx.x;
    const int x0    = (gx >> 3) * TX;        // 5 spatial x-tiles
    const int cg    = gx & 7;                // 8 channel groups, dispatch-adjacent
    const int y0    = blockIdx.y * TY;
    const int b     = blockIdx.z;
    const int cbase = cg * CPB;
    const int d     = dil[0];

    const int lane = tid & 63;
    const int qx   = lane & 7;        // x-quad within tile row
    const int ty   = lane >> 3;       // row within tile
    const int c0   = (tid >> 6) * CPW;   // {0,2,4,6} -- wave-private channel pair

    const int x = x0 + 4 * qx;
    const int y = y0 + ty;
    const float* kb = kern + (size_t)b * KK * HW + (size_t)y * W + x;

    if (d == 1) {
        // ---- stage fm: THIS WAVE's 2 channels x 12 rows x 10 float4, OOB -> 0.
        // 240 float4 over 64 lanes (3.75 iters). No cross-wave sharing.
        const float* fmb = fm + ((size_t)b * C + cbase) * HW;
        for (int idx = lane; idx < CPW * FR * 10; idx += 64) {   // 240 float4
            const int ch  = idx / (FR * 10);          // 0..1
            const int rem = idx - ch * (FR * 10);
            const int r   = rem / 10;
            const int f4  = rem - r * 10;
            const int gy  = y0 - 2 + r;
            const int gxc = x0 - 4 + 4 * f4;   // mult of 4: float4 all-in or all-out
            float4 v = make_float4(0.f, 0.f, 0.f, 0.f);
            if (gy >= 0 && gy < H && gxc >= 0 && gxc < W)
                v = *(const float4*)(fmb + (size_t)(c0 + ch) * HW + (size_t)gy * W + gxc);
            float* dst = &fmlds[((c0 + ch) * FR + r) * FS + 4 * f4];  // 8B-aligned (FS even)
            *(float2*)dst       = make_float2(v.x, v.y);
            *(float2*)(dst + 2) = make_float2(v.z, v.w);
        }
        // NO __syncthreads(): LDS regions are wave-private; lgkmcnt orders
        // this wave's ds_writes against its ds_reads below.

        float acc[CPW][4];
#pragma unroll
        for (int c = 0; c < CPW; ++c)
#pragma unroll
            for (int p = 0; p < 4; ++p) acc[c][p] = 0.f;

#pragma unroll
        for (int i = 0; i < K; ++i) {
            // weights for this tap row, straight from global (flipped); no masking
            // needed: OOB fm positions are zero in LDS.
            float wr[K][4];
#pragma unroll
            for (int j = 0; j < K; ++j) {
                const int t = i * K + j;
                const float4 wv = *(const float4*)(kb + (size_t)(KK - 1 - t) * HW);
                wr[j][0] = wv.x; wr[j][1] = wv.y; wr[j][2] = wv.z; wr[j][3] = wv.w;
            }
            // fm windows from LDS: per channel 8 floats (cols x-2..x+5), 4x b64
            float win[CPW][8];
#pragma unroll
            for (int c = 0; c < CPW; ++c) {
                const int base = ((c0 + c) * FR + ty + i) * FS + 4 * qx + 2;
#pragma unroll
                for (int k = 0; k < 4; ++k) {
                    const float2 t2 = *(const float2*)&fmlds[base + 2 * k];
                    win[c][2 * k]     = t2.x;
                    win[c][2 * k + 1] = t2.y;
                }
            }
#pragma unroll
            for (int c = 0; c < CPW; ++c)
#pragma unroll
                for (int j = 0; j < K; ++j)
#pragma unroll
                    for (int p = 0; p < 4; ++p)
                        acc[c][p] = fmaf(wr[j][p], win[c][p + j], acc[c][p]);
        }

        float* ob = out + ((size_t)b * C + cbase + c0) * HW + (size_t)y * W + x;
#pragma unroll
        for (int c = 0; c < CPW; ++c) {
            const float4 o = {acc[c][0], acc[c][1], acc[c][2], acc[c][3]};
            *(float4*)(ob + (size_t)c * HW) = o;
        }
    } else {
        // Generic-dilation fallback (never taken in this bench; d==1 there).
        const float* fb = fm  + ((size_t)b * C + cbase + c0) * HW;
        float*       ob = out + ((size_t)b * C + cbase + c0) * HW + (size_t)y * W + x;
#pragma unroll 1
        for (int p = 0; p < 4; ++p) {
            const int xx = x + p;
            float wgt[KK];
            int   offs[KK];
#pragma unroll 1
            for (int i = 0; i < K; ++i) {
                const int  yy  = y + (i - 2) * d;
                const bool yok = (yy >= 0) && (yy < H);
                const int  yc  = min(max(yy, 0), H - 1);
#pragma unroll 1
                for (int j = 0; j < K; ++j) {
                    const int  xc  = xx + (j - 2) * d;
                    const bool ok  = yok && (xc >= 0) && (xc < W);
                    const int  xcc = min(max(xc, 0), W - 1);
                    const int  t   = i * K + j;
                    wgt[t]  = ok ? kb[(size_t)(KK - 1 - t) * HW + p] : 0.f;
                    offs[t] = yc * W + xcc;
                }
            }
#pragma unroll 1
            for (int c = 0; c < CPW; ++c) {
                const float* fc = fb + (size_t)c * HW;
                float a2 = 0.f;
#pragma unroll 1
                for (int t = 0; t < KK; ++t) a2 = fmaf(wgt[t], fc[offs[t]], a2);
                ob[(size_t)c * HW + p] = a2;
            }
        }
    }
}

extern "C" void kernel_launch(void* const* d_in, const int* in_sizes, int n_in,
                              void* d_out, int out_size, void* d_ws, size_t ws_size,
                              hipStream_t stream)
{
    const float* fm   = (const float*)d_in[0];
    const float* kern = (const float*)d_in[1];
    const int*   dil  = (const int*)d_in[2];
    float*       out  = (float*)d_out;

    dim3 grid(8 * (W / TX), H / TY, BS);   // 40 x 20 x 4 = 3200 blocks
    kconv_kernel<<<grid, dim3(BLK), 0, stream>>>(fm, kern, dil, out);
}

// Round 3
// 97.312 us; speedup vs baseline: 1.0287x; 1.0287x over previous
//
#include <hip/hip_runtime.h>

#define K    5
#define KK   25
#define H    160
#define W    160
#define C    64
#define BS   4
#define HW   (H * W)

#define TX   32          // tile width (pixels)
#define TY   8           // tile height (rows)
#define CPB  8           // channels per block (R9: 16->8 to halve LDS)
#define CPW  2           // channels per thread
#define BLK  256

#define FR   (TY + 4)    // fm rows staged (2 halo top + 2 bottom) = 12
#define FS   46          // fm LDS row stride: conflict-free b64 window reads (R7)

// R12 = resubmit of R11/R9 (best verified: 96.1us); R11's bench failed on
// container acquisition (infra, not kernel). Decomposition of the bench
// total: 2x ~43us harness poison fills (256MiB each, 78% HBM peak) +
// ~10-14us conv dispatch, vs a ~10us HBM traffic floor (26.2MB fm + 10.2MB
// weights in, 26.2MB out @ 6.3TB/s). The conv kernel is within a few us of
// its memory roofline and ~86% of dur_us is fixed harness cost -- remaining
// headroom is below the observed bench noise (+-4us).
__global__ __launch_bounds__(BLK) void kconv_kernel(
    const float* __restrict__ fm,
    const float* __restrict__ kern,
    const int*  __restrict__ dil,
    float* __restrict__ out)
{
    __shared__ float fmlds[CPB * FR * FS];   // 17664 B

    const int tid   = threadIdx.x;
    const int gx    = blockIdx.x;
    const int x0    = (gx >> 3) * TX;        // 5 spatial x-tiles
    const int cg    = gx & 7;                // 8 channel groups, dispatch-adjacent
    const int y0    = blockIdx.y * TY;
    const int b     = blockIdx.z;
    const int cbase = cg * CPB;
    const int d     = dil[0];

    const int lane = tid & 63;
    const int qx   = lane & 7;        // x-quad within tile row
    const int ty   = lane >> 3;       // row within tile
    const int c0   = (tid >> 6) * CPW;   // {0,2,4,6}

    const int x = x0 + 4 * qx;
    const int y = y0 + ty;
    const float* kb = kern + (size_t)b * KK * HW + (size_t)y * W + x;

    if (d == 1) {
        // ---- stage fm tile: 8 ch x 12 rows x 10 float4 (cols x0-4..x0+35), OOB -> 0
        const float* fmb = fm + ((size_t)b * C + cbase) * HW;
        for (int idx = tid; idx < CPB * FR * 10; idx += BLK) {   // 960 float4
            const int ch  = idx / (FR * 10);
            const int rem = idx - ch * (FR * 10);
            const int r   = rem / 10;
            const int f4  = rem - r * 10;
            const int gy  = y0 - 2 + r;
            const int gxc = x0 - 4 + 4 * f4;   // mult of 4: float4 all-in or all-out
            float4 v = make_float4(0.f, 0.f, 0.f, 0.f);
            if (gy >= 0 && gy < H && gxc >= 0 && gxc < W)
                v = *(const float4*)(fmb + (size_t)ch * HW + (size_t)gy * W + gxc);
            float* dst = &fmlds[(ch * FR + r) * FS + 4 * f4];    // 8B-aligned (FS even)
            *(float2*)dst       = make_float2(v.x, v.y);
            *(float2*)(dst + 2) = make_float2(v.z, v.w);
        }
        __syncthreads();

        float acc[CPW][4];
#pragma unroll
        for (int c = 0; c < CPW; ++c)
#pragma unroll
            for (int p = 0; p < 4; ++p) acc[c][p] = 0.f;

#pragma unroll
        for (int i = 0; i < K; ++i) {
            // weights for this tap row, straight from global (flipped); no masking
            // needed: OOB fm positions are zero in LDS.
            float wr[K][4];
#pragma unroll
            for (int j = 0; j < K; ++j) {
                const int t = i * K + j;
                const float4 wv = *(const float4*)(kb + (size_t)(KK - 1 - t) * HW);
                wr[j][0] = wv.x; wr[j][1] = wv.y; wr[j][2] = wv.z; wr[j][3] = wv.w;
            }
            // fm windows from LDS: per channel 8 floats (cols x-2..x+5), 4x b64
            float win[CPW][8];
#pragma unroll
            for (int c = 0; c < CPW; ++c) {
                const int base = ((c0 + c) * FR + ty + i) * FS + 4 * qx + 2;
#pragma unroll
                for (int k = 0; k < 4; ++k) {
                    const float2 t2 = *(const float2*)&fmlds[base + 2 * k];
                    win[c][2 * k]     = t2.x;
                    win[c][2 * k + 1] = t2.y;
                }
            }
#pragma unroll
            for (int c = 0; c < CPW; ++c)
#pragma unroll
                for (int j = 0; j < K; ++j)
#pragma unroll
                    for (int p = 0; p < 4; ++p)
                        acc[c][p] = fmaf(wr[j][p], win[c][p + j], acc[c][p]);
        }

        float* ob = out + ((size_t)b * C + cbase + c0) * HW + (size_t)y * W + x;
#pragma unroll
        for (int c = 0; c < CPW; ++c) {
            const float4 o = {acc[c][0], acc[c][1], acc[c][2], acc[c][3]};
            *(float4*)(ob + (size_t)c * HW) = o;
        }
    } else {
        // Generic-dilation fallback (never taken in this bench; d==1 there).
        const float* fb = fm  + ((size_t)b * C + cbase + c0) * HW;
        float*       ob = out + ((size_t)b * C + cbase + c0) * HW + (size_t)y * W + x;
#pragma unroll 1
        for (int p = 0; p < 4; ++p) {
            const int xx = x + p;
            float wgt[KK];
            int   offs[KK];
#pragma unroll 1
            for (int i = 0; i < K; ++i) {
                const int  yy  = y + (i - 2) * d;
                const bool yok = (yy >= 0) && (yy < H);
                const int  yc  = min(max(yy, 0), H - 1);
#pragma unroll 1
                for (int j = 0; j < K; ++j) {
                    const int  xc  = xx + (j - 2) * d;
                    const bool ok  = yok && (xc >= 0) && (xc < W);
                    const int  xcc = min(max(xc, 0), W - 1);
                    const int  t   = i * K + j;
                    wgt[t]  = ok ? kb[(size_t)(KK - 1 - t) * HW + p] : 0.f;
                    offs[t] = yc * W + xcc;
                }
            }
#pragma unroll 1
            for (int c = 0; c < CPW; ++c) {
                const float* fc = fb + (size_t)c * HW;
                float a2 = 0.f;
#pragma unroll 1
                for (int t = 0; t < KK; ++t) a2 = fmaf(wgt[t], fc[offs[t]], a2);
                ob[(size_t)c * HW + p] = a2;
            }
        }
    }
}

extern "C" void kernel_launch(void* const* d_in, const int* in_sizes, int n_in,
                              void* d_out, int out_size, void* d_ws, size_t ws_size,
                              hipStream_t stream)
{
    const float* fm   = (const float*)d_in[0];
    const float* kern = (const float*)d_in[1];
    const int*   dil  = (const int*)d_in[2];
    float*       out  = (float*)d_out;

    dim3 grid(8 * (W / TX), H / TY, BS);   // 40 x 20 x 4 = 3200 blocks
    kconv_kernel<<<grid, dim3(BLK), 0, stream>>>(fm, kern, dil, out);
}